// Round 13
// baseline (610.049 us; speedup 1.0000x reference)
//
#include <hip/hip_runtime.h>
#include <hip/hip_fp16.h>
#include <cstdint>

#define GRAPHS 128

__device__ __forceinline__ int lane_bcast_i(int v, int l) {
  return __builtin_amdgcn_readlane(v, l);
}
__device__ __forceinline__ float lane_bcast_f(float v, int l) {
  return __int_as_float(__builtin_amdgcn_readlane(__float_as_int(v), l));
}
// async global->LDS DMA, 16B/lane (dwordx4): HW places at wave-uniform base + lane*16
__device__ __forceinline__ void load_lds16(const __half* g, __half* l) {
  __builtin_amdgcn_global_load_lds(
      (const __attribute__((address_space(1))) void*)g,
      (__attribute__((address_space(3))) void*)l, 16, 0, 0);
}
#define WAIT_VM0   __builtin_amdgcn_s_waitcnt(0x0F70)  // vmcnt(0) only
#define WAIT_LGKM0 __builtin_amdgcn_s_waitcnt(0xC07F)  // lgkmcnt(0) only

// ---------------- edge prep: degree -> scan -> scatter (CSR by dst) ----------------

__global__ __launch_bounds__(256) void k_deg(const int* __restrict__ ei, int E, int ET,
                                             int* __restrict__ deg) {
  int e = blockIdx.x * 256 + threadIdx.x;
  if (e >= ET) return;
  int d = (e < E) ? ei[E + e] : (e - E);
  atomicAdd(&deg[d], 1);
}

__global__ __launch_bounds__(256) void k_s1(const int* __restrict__ deg, int N,
                                            int* __restrict__ bsum) {
  int b = blockIdx.x, tid = threadIdx.x;
  int i0 = b * 1024 + tid * 4;
  int s = 0;
#pragma unroll
  for (int e = 0; e < 4; ++e) { int i = i0 + e; if (i < N) s += deg[i]; }
#pragma unroll
  for (int o = 32; o; o >>= 1) s += __shfl_xor(s, o);
  __shared__ int wt[4];
  int lane = tid & 63, wid = tid >> 6;
  if (lane == 0) wt[wid] = s;
  __syncthreads();
  if (tid == 0) bsum[b] = wt[0] + wt[1] + wt[2] + wt[3];
}

__global__ void k_s2(int* bsum, int nb) {
  if (threadIdx.x == 0) {
    int run = 0;
    for (int i = 0; i < nb; ++i) { int t = bsum[i]; bsum[i] = run; run += t; }
  }
}

__global__ __launch_bounds__(256) void k_s3(int* __restrict__ deg_cursor,
                                            const int* __restrict__ bsum,
                                            int* __restrict__ rowptr, int N) {
  int b = blockIdx.x, tid = threadIdx.x;
  int lane = tid & 63, wid = tid >> 6;
  int i0 = b * 1024 + tid * 4;
  int d[4];
#pragma unroll
  for (int e = 0; e < 4; ++e) { int i = i0 + e; d[e] = (i < N) ? deg_cursor[i] : 0; }
  int p0 = d[0], p1 = p0 + d[1], p2 = p1 + d[2], p3 = p2 + d[3];
  int incl = p3;
#pragma unroll
  for (int o = 1; o < 64; o <<= 1) { int u = __shfl_up(incl, o); if (lane >= o) incl += u; }
  __shared__ int wt[4];
  if (lane == 63) wt[wid] = incl;
  __syncthreads();
  int woff = 0;
  for (int w = 0; w < wid; ++w) woff += wt[w];
  int ex = bsum[b] + woff + incl - p3;
  int pre[4] = {0, p0, p1, p2};
#pragma unroll
  for (int e = 0; e < 4; ++e) {
    int i = i0 + e;
    if (i < N) { int st = ex + pre[e]; deg_cursor[i] = st; rowptr[i + 1] = st + d[e]; }
  }
  if (b == 0 && tid == 0) rowptr[0] = 0;
}

__global__ __launch_bounds__(256) void k_scatter(const int* __restrict__ ei, int E, int ET,
                                                 int* __restrict__ cursor,
                                                 int* __restrict__ csrs) {
  int e = blockIdx.x * 256 + threadIdx.x;
  if (e >= ET) return;
  int s, d;
  if (e < E) { s = ei[e]; d = ei[E + e]; } else { s = d = e - E; }
  int pos = atomicAdd(&cursor[d], 1);
  csrs[pos] = s;
}

// ---------------- GEMM (64x64 tile, 4x4/thread), fp16 C, fused attention dots ----------------

__global__ __launch_bounds__(256) void k_gemm_att(
    const float* __restrict__ A, const float* __restrict__ B, __half* __restrict__ C,
    const float* __restrict__ attS, const float* __restrict__ attD,
    float* __restrict__ aS, float* __restrict__ aD, int M, int K, int NC, int astr) {
  __shared__ float As[64][68];
  __shared__ float Bs[64][64];
  int tid = threadIdx.x;
  int tx = tid & 15, ty = tid >> 4;
  int m0 = blockIdx.x * 64, n0 = blockIdx.y * 64;
  float acc[4][4] = {};
  for (int kc = 0; kc < K; kc += 64) {
    int r = tid >> 4;
    int f4 = tid & 15;
#pragma unroll
    for (int p = 0; p < 4; ++p) {
      int row = r + p * 16;
      int gm = m0 + row;
      float4 v = make_float4(0.f, 0.f, 0.f, 0.f);
      if (gm < M) v = *(const float4*)&A[(size_t)gm * K + kc + f4 * 4];
      As[f4 * 4 + 0][row] = v.x; As[f4 * 4 + 1][row] = v.y;
      As[f4 * 4 + 2][row] = v.z; As[f4 * 4 + 3][row] = v.w;
      float4 w = *(const float4*)&B[(size_t)(kc + row) * NC + n0 + f4 * 4];
      *(float4*)&Bs[row][f4 * 4] = w;
    }
    __syncthreads();
#pragma unroll 4
    for (int k = 0; k < 64; ++k) {
      float4 a4 = *(const float4*)&As[k][ty * 4];
      float4 b4 = *(const float4*)&Bs[k][tx * 4];
      acc[0][0] += a4.x * b4.x; acc[0][1] += a4.x * b4.y; acc[0][2] += a4.x * b4.z; acc[0][3] += a4.x * b4.w;
      acc[1][0] += a4.y * b4.x; acc[1][1] += a4.y * b4.y; acc[1][2] += a4.y * b4.z; acc[1][3] += a4.y * b4.w;
      acc[2][0] += a4.z * b4.x; acc[2][1] += a4.z * b4.y; acc[2][2] += a4.z * b4.z; acc[2][3] += a4.z * b4.w;
      acc[3][0] += a4.w * b4.x; acc[3][1] += a4.w * b4.y; acc[3][2] += a4.w * b4.z; acc[3][3] += a4.w * b4.w;
    }
    __syncthreads();
  }
  int head = blockIdx.y;
  float asv[4], adv[4];
#pragma unroll
  for (int ci = 0; ci < 4; ++ci) { asv[ci] = attS[n0 + tx * 4 + ci]; adv[ci] = attD[n0 + tx * 4 + ci]; }
#pragma unroll
  for (int ri = 0; ri < 4; ++ri) {
    int gm = m0 + ty * 4 + ri;
    if (gm < M) {
      __half2 p01 = __halves2half2(__float2half(acc[ri][0]), __float2half(acc[ri][1]));
      __half2 p23 = __halves2half2(__float2half(acc[ri][2]), __float2half(acc[ri][3]));
      size_t cidx = (size_t)gm * NC + n0 + tx * 4;
      *(__half2*)&C[cidx] = p01;
      *(__half2*)&C[cidx + 2] = p23;
    }
    float s = acc[ri][0] * asv[0] + acc[ri][1] * asv[1] + acc[ri][2] * asv[2] + acc[ri][3] * asv[3];
    float d = acc[ri][0] * adv[0] + acc[ri][1] * adv[1] + acc[ri][2] * adv[2] + acc[ri][3] * adv[3];
#pragma unroll
    for (int o2 = 1; o2 < 16; o2 <<= 1) { s += __shfl_xor(s, o2); d += __shfl_xor(d, o2); }
    if (tx == 0 && gm < M) { aS[(size_t)gm * astr + head] = s; aD[(size_t)gm * astr + head] = d; }
  }
}

// ---------------- single-head wave-per-(node,head) softmax + wide-DMA fp16 aggregation -------
// Each wave: one node, one head (blockIdx.y). Row slice = 64 halves = 128B; 16-edge batches,
// 2 DMA instrs/batch (each covers 8 rows). Layer1 runs as 3 head-split planes (3x waves).

template <bool DOELU, bool POOL>
__global__ __launch_bounds__(256) void k_agg1(
    const int* __restrict__ rowptr, const int* __restrict__ csrs,
    const __half* __restrict__ xp, const float* __restrict__ aS, const float* __restrict__ aD,
    const float* __restrict__ bias, float* __restrict__ out,
    const int* __restrict__ batch, float* __restrict__ pooled, float* __restrict__ gcnt,
    int N, int astr, int rowstr, int outstr) {
  __shared__ __half stage[4][1024];
  int wv = (blockIdx.x * blockDim.x + threadIdx.x) >> 6;
  int lane = threadIdx.x & 63;
  int wid = (threadIdx.x >> 6) & 3;
  if (wv >= N) return;
  __half* st = stage[wid];
  int head = blockIdx.y;
  int coloff = head * 64;
  int n = wv;
  int start = rowptr[n], end = rowptr[n + 1];
  float ad = aD[(size_t)n * astr + head];
  float m = -1e30f, s = 0.f, al = 0.f, cf = 0.f, acc = 0.f;
  // ---- softmax phase: lane-per-edge ----
  int myS = -1;
  int j = start + lane;
  if (j < end) {
    myS = csrs[j];
    float v = aS[(size_t)myS * astr + head] + ad;
    v = v > 0.f ? v : 0.2f * v;
    al = v; m = v; s = 1.f;
  }
  for (int jj = j + 64; jj < end; jj += 64) {  // degree > 64 (rare)
    int sb = csrs[jj];
    float v = aS[(size_t)sb * astr + head] + ad;
    v = v > 0.f ? v : 0.2f * v;
    float M = fmaxf(m, v);
    s = s * __expf(m - M) + __expf(v - M);
    m = M;
  }
  {
    float mm = m, ss = s;
#pragma unroll
    for (int o = 1; o < 64; o <<= 1) {
      float om = __shfl_xor(mm, o), os = __shfl_xor(ss, o);
      float M = fmaxf(mm, om);
      ss = ss * __expf(mm - M) + os * __expf(om - M);
      mm = M;
    }
    m = mm;
    s = 1.0f / fmaxf(ss, 1e-16f);
  }
  if (myS >= 0) cf = __expf(al - m) * s;
  // ---- gather phase: 16-edge batches, 2 wide DMAs per batch ----
  for (int base = start; base < end; base += 64) {
    int cnt = min(64, end - base);
    int sreg; float dd;
    if (base == start) {
      sreg = myS; dd = cf;
    } else {  // degree > 64 spillover (rare)
      int jj = base + lane; sreg = 0; dd = 0.f;
      if (jj < end) {
        sreg = csrs[jj];
        float v = aS[(size_t)sreg * astr + head] + ad;
        v = v > 0.f ? v : 0.2f * v;
        dd = __expf(v - m) * s;
      }
    }
    for (int e = 0; e < cnt; e += 16) {
      WAIT_LGKM0;  // prior batch's LDS reads drained before DMA overwrites slot
#pragma unroll
      for (int k = 0; k < 2; ++k) {
        int ee = min(e + 8 * k + (lane >> 3), cnt - 1);
        int sb = __shfl(sreg, ee);
        const __half* g = xp + (size_t)sb * rowstr + coloff + (lane & 7) * 8;
        load_lds16(g, st + k * 512);   // 8 rows of 64 halves per DMA
      }
      WAIT_VM0;  // all DMAs landed in LDS
#pragma unroll
      for (int u = 0; u < 16; ++u) {
        float c = (e + u < cnt) ? lane_bcast_f(dd, e + u) : 0.f;
        acc = fmaf(c, __half2float(st[(u >> 3) * 512 + (u & 7) * 64 + lane]), acc);
      }
    }
  }
  // ---- epilogue ----
  if (POOL) {
    float val = acc + bias[lane];
    int g = batch[n];
    atomicAdd(&pooled[g * 64 + lane], val);
    if (lane == 0) atomicAdd(&gcnt[g], 1.0f);
  } else {
    float v = acc + bias[coloff + lane];
    if (DOELU) v = v > 0.f ? v : __expf(v) - 1.0f;
    out[(size_t)n * outstr + coloff + lane] = v;
  }
}

// ---------------- final: mean + linear ----------------

__global__ __launch_bounds__(64) void k_final(const float* __restrict__ pooled,
                                              const float* __restrict__ gcnt,
                                              const float* __restrict__ lw,
                                              const float* __restrict__ lb,
                                              float* __restrict__ out) {
  int g = blockIdx.x, c = threadIdx.x;
  float inv = 1.0f / fmaxf(gcnt[g], 1.0f);
  float pv = pooled[g * 64 + c] * inv;
#pragma unroll
  for (int k = 0; k < 10; ++k) {
    float v = pv * lw[c * 10 + k];
#pragma unroll
    for (int o = 1; o < 64; o <<= 1) v += __shfl_xor(v, o);
    if (c == 0) out[g * 10 + k] = v + lb[k];
  }
}

extern "C" void kernel_launch(void* const* d_in, const int* in_sizes, int n_in,
                              void* d_out, int out_size, void* d_ws, size_t ws_size,
                              hipStream_t stream) {
  const float* x = (const float*)d_in[0];
  const int* ei = (const int*)d_in[1];
  const int* batch = (const int*)d_in[2];
  const float* W1 = (const float*)d_in[3];
  const float* as1 = (const float*)d_in[4];
  const float* ad1 = (const float*)d_in[5];
  const float* b1 = (const float*)d_in[6];
  const float* W2 = (const float*)d_in[7];
  const float* as2 = (const float*)d_in[8];
  const float* ad2 = (const float*)d_in[9];
  const float* b2 = (const float*)d_in[10];
  const float* lw = (const float*)d_in[11];
  const float* lb = (const float*)d_in[12];
  float* out = (float*)d_out;

  const int N = in_sizes[2];        // 50000
  const int E = in_sizes[1] / 2;    // 800000
  const int ET = E + N;             // + self loops
  const int F = in_sizes[0] / N;    // 128
  const int HC = in_sizes[6];       // 192
  const int LH = in_sizes[10];      // 64

  size_t off = 0;
  auto alo = [&](size_t bytes) -> char* {
    char* p = (char*)d_ws + off;
    off += (bytes + 255) & ~(size_t)255;
    return p;
  };
  int* cursor = (int*)alo((size_t)N * 4);
  float* pooled = (float*)alo((size_t)GRAPHS * 64 * 4);
  float* gcnt = (float*)alo((size_t)GRAPHS * 4);
  size_t zbytes = off;
  int* rowptr = (int*)alo(((size_t)N + 1) * 4);
  int* csrs = (int*)alo((size_t)ET * 4);
  float* aS1 = (float*)alo((size_t)N * 4 * 4);      // stride-4 padded
  float* aD1 = (float*)alo((size_t)N * 4 * 4);
  float* aS2 = (float*)alo((size_t)N * 4);
  float* aD2 = (float*)alo((size_t)N * 4);
  int* bsum = (int*)alo(64 * 4);
  __half* xp1 = (__half*)alo((size_t)N * 192 * 2 + 512);
  float* h1 = (float*)alo((size_t)N * 192 * 4);
  __half* xp2 = (__half*)alo((size_t)N * 64 * 2 + 512);

  hipMemsetAsync(d_ws, 0, zbytes, stream);
  int eb = (ET + 255) / 256;
  k_deg<<<eb, 256, 0, stream>>>(ei, E, ET, cursor);
  int nb = (N + 1023) / 1024;
  k_s1<<<nb, 256, 0, stream>>>(cursor, N, bsum);
  k_s2<<<1, 64, 0, stream>>>(bsum, nb);
  k_s3<<<nb, 256, 0, stream>>>(cursor, bsum, rowptr, N);
  k_scatter<<<eb, 256, 0, stream>>>(ei, E, ET, cursor, csrs);

  dim3 g1((N + 63) / 64, HC / 64);
  k_gemm_att<<<g1, 256, 0, stream>>>(x, W1, xp1, as1, ad1, aS1, aD1, N, F, HC, 4);
  int ab = (N + 3) / 4;
  dim3 ga1(ab, 3);  // head-split: 3x waves, each wave = one (node, head)
  k_agg1<true, false><<<ga1, 256, 0, stream>>>(rowptr, csrs, xp1, aS1, aD1, b1, h1,
                                               nullptr, nullptr, nullptr, N, 4, 192, 192);
  dim3 g2((N + 63) / 64, LH / 64);
  k_gemm_att<<<g2, 256, 0, stream>>>(h1, W2, xp2, as2, ad2, aS2, aD2, N, HC, LH, 1);
  dim3 ga2(ab, 1);
  k_agg1<false, true><<<ga2, 256, 0, stream>>>(rowptr, csrs, xp2, aS2, aD2, b2, nullptr,
                                               batch, pooled, gcnt, N, 1, 64, 64);
  k_final<<<GRAPHS, 64, 0, stream>>>(pooled, gcnt, lw, lb, out);
}